// Round 4
// baseline (422.413 us; speedup 1.0000x reference)
//
#include <hip/hip_runtime.h>
#include <hip/hip_fp16.h>

#define DD 128
#define BK_SHIFT 6
#define BK_NODES 64   // nodes per bucket

typedef __attribute__((ext_vector_type(8))) short bf16x8;
typedef __attribute__((ext_vector_type(4))) float f32x4;

static __device__ __forceinline__ ushort f2bf(float f) {
    unsigned u = __float_as_uint(f);
    u = u + 0x7FFF + ((u >> 16) & 1);   // RNE
    return (ushort)(u >> 16);
}
static __device__ __forceinline__ float bf2f(ushort h) {
    return __uint_as_float(((unsigned)h) << 16);
}

// ---------------- weights -> bf16 hi/lo split ----------------
__global__ void prep_w(const float* __restrict__ W0, const float* __restrict__ W1,
                       const float* __restrict__ W2, const float* __restrict__ W3,
                       const float* __restrict__ W4, const float* __restrict__ W5,
                       ushort* __restrict__ Whi, ushort* __restrict__ Wlo) {
    int idx = blockIdx.x * 256 + threadIdx.x;   // 0 .. 6*16384-1
    int wi = idx >> 14;
    int off = idx & 16383;
    float a;
    switch (wi) {
        case 0: a = W0[off]; break;
        case 1: a = W1[off]; break;
        case 2: a = W2[off]; break;
        case 3: a = W3[off]; break;
        case 4: a = W4[off]; break;
        default: a = W5[off]; break;
    }
    ushort h = f2bf(a);
    Whi[idx] = h;
    Wlo[idx] = f2bf(a - bf2f(h));
}

// ---------------- CSR build, stage 1: bucket histogram (LDS-privatized) ----------------
__global__ __launch_bounds__(256) void bucket_hist(const int* __restrict__ dst,
                                                   int* __restrict__ bcnt, int E, int NB) {
    extern __shared__ int h[];   // NB ints
    int t = threadIdx.x;
    for (int i = t; i < NB; i += 256) h[i] = 0;
    __syncthreads();
    int stride = gridDim.x * 256;
    for (int e = blockIdx.x * 256 + t; e < E; e += stride)
        atomicAdd(&h[dst[e] >> BK_SHIFT], 1);
    __syncthreads();
    for (int i = t; i < NB; i += 256) {
        int v = h[i];
        if (v) atomicAdd(&bcnt[i], v);
    }
}

// ---------------- CSR build, stage 2: tiny scan over buckets ----------------
__global__ __launch_bounds__(1024) void bucket_scan(const int* __restrict__ bcnt,
                                                    int* __restrict__ bptr,
                                                    int* __restrict__ bcur, int NB) {
    __shared__ int s[1024];
    int t = threadIdx.x;
    int v = (t < NB) ? bcnt[t] : 0;
    s[t] = v;
    __syncthreads();
    for (int off = 1; off < 1024; off <<= 1) {
        int x = (t >= off) ? s[t - off] : 0;
        __syncthreads();
        s[t] += x;
        __syncthreads();
    }
    if (t < NB) {
        int excl = s[t] - v;
        bptr[t] = excl;
        bcur[t] = excl;
        if (t == NB - 1) bptr[NB] = s[t];
    }
}

// ---------------- CSR build, stage 3: bin edges (write-local streams) ----------------
__global__ __launch_bounds__(256) void bin_edges(const int* __restrict__ src,
                                                 const int* __restrict__ dst,
                                                 int* __restrict__ bcur,
                                                 unsigned* __restrict__ ebuf, int E) {
    int e = blockIdx.x * 256 + threadIdx.x;
    if (e < E) {
        int d = dst[e];
        int p = atomicAdd(&bcur[d >> BK_SHIFT], 1);
        ebuf[p] = ((unsigned)src[e] << BK_SHIFT) | (unsigned)(d & (BK_NODES - 1));
    }
}

// ---------------- CSR build, stage 4: per-bucket rowptr + csr scatter ----------------
__global__ __launch_bounds__(256) void build_csr(const unsigned* __restrict__ ebuf,
                                                 const int* __restrict__ bptr,
                                                 int* __restrict__ rowptr,
                                                 int* __restrict__ csr_src, int N) {
    __shared__ int cnt[BK_NODES];
    __shared__ int cur[BK_NODES];
    int b = blockIdx.x;
    int t = threadIdx.x;
    int beg = bptr[b], end = bptr[b + 1];
    if (b == 0 && t == 0) rowptr[0] = 0;
    if (t < BK_NODES) cnt[t] = 0;
    __syncthreads();
    for (int e = beg + t; e < end; e += 256)
        atomicAdd(&cnt[ebuf[e] & (BK_NODES - 1)], 1);
    __syncthreads();
    if (t < 64) {   // one wave: scan 64 counts
        int v = cnt[t];
        int inc = v;
#pragma unroll
        for (int off = 1; off < 64; off <<= 1) {
            int x = __shfl_up(inc, off);
            if (t >= off) inc += x;
        }
        cur[t] = beg + inc - v;          // exclusive
        int node = b * BK_NODES + t;
        if (node < N) rowptr[node + 1] = beg + inc;
    }
    __syncthreads();
    for (int e = beg + t; e < end; e += 256) {
        unsigned v = ebuf[e];
        int p = atomicAdd(&cur[v & (BK_NODES - 1)], 1);
        csr_src[p] = (int)(v >> BK_SHIFT);
    }
}

// ---------------- segment max gather (half rows), 8-deep ILP ----------------
__global__ __launch_bounds__(256) void segmax_half(const __half* __restrict__ m,
                                                   const int* __restrict__ rowptr,
                                                   const int* __restrict__ csr_src,
                                                   __half* __restrict__ agg, int n) {
    int node = blockIdx.x * 4 + (threadIdx.x >> 6);
    if (node >= n) return;
    int lane = threadIdx.x & 63;
    int beg = rowptr[node], end = rowptr[node + 1];
    const __half* mp = m + lane * 2;
    float2 mx[8];
#pragma unroll
    for (int u = 0; u < 8; ++u) mx[u] = make_float2(0.f, 0.f);   // relu'd inputs >= 0
    int e = beg;
    for (; e + 8 <= end; e += 8) {
#pragma unroll
        for (int u = 0; u < 8; ++u) {
            int s = csr_src[e + u];
            float2 v = __half22float2(*(const __half2*)(mp + (size_t)s * DD));
            mx[u].x = fmaxf(mx[u].x, v.x);
            mx[u].y = fmaxf(mx[u].y, v.y);
        }
    }
    for (; e < end; ++e) {
        int s = csr_src[e];
        float2 v = __half22float2(*(const __half2*)(mp + (size_t)s * DD));
        mx[0].x = fmaxf(mx[0].x, v.x);
        mx[0].y = fmaxf(mx[0].y, v.y);
    }
#pragma unroll
    for (int u = 4; u > 0; u >>= 1)
#pragma unroll
        for (int k = 0; k < u; ++k) {
            mx[k].x = fmaxf(mx[k].x, mx[k + u].x);
            mx[k].y = fmaxf(mx[k].y, mx[k + u].y);
        }
    *(__half2*)(agg + (size_t)node * DD + lane * 2) = __float22half2_rn(mx[0]);
}

// ---------------- MFMA GEMM: out = A@WA^T (+ G@WG^T) + bias ----------------
// split-bf16: X = hi + lo; X*W ~= hi*Whi + lo*Whi + hi*Wlo  (error ~2^-16 rel)
// EPI: 0 = none (f32 out), 1 = relu (half out), 2 = relu + row-L2-norm (f32 out)
template <int EPI, bool FUSED>
__global__ __launch_bounds__(256, 2) void gemm_mfma(
    const float* __restrict__ A, const ushort* __restrict__ WAhi, const ushort* __restrict__ WAlo,
    const __half* __restrict__ G, const ushort* __restrict__ WGhi, const ushort* __restrict__ WGlo,
    const float* __restrict__ bias, void* __restrict__ outv, int nrows) {
    extern __shared__ char smem[];
    int tid = threadIdx.x;
    int lane = tid & 63;
    int w = tid >> 6;
    int l16 = lane & 15;
    int lg = lane >> 4;
    int koff = lg * 8;
    int blk0 = blockIdx.x * 128;
    int rbase = blk0 + w * 32;

    f32x4 zero4 = {0.f, 0.f, 0.f, 0.f};
    f32x4 acc[2][8];
#pragma unroll
    for (int mt = 0; mt < 2; ++mt)
#pragma unroll
        for (int nt = 0; nt < 8; ++nt) acc[mt][nt] = zero4;

    // ---- pass 1: A (f32) ----
#pragma unroll
    for (int kk = 0; kk < 4; ++kk) {
        int k0 = kk * 32 + koff;
        bf16x8 ah[2], al[2];
#pragma unroll
        for (int mt = 0; mt < 2; ++mt) {
            int row = rbase + mt * 16 + l16;
            float va[8];
            if (row < nrows) {
                float4 v0 = *(const float4*)(A + (size_t)row * DD + k0);
                float4 v1 = *(const float4*)(A + (size_t)row * DD + k0 + 4);
                va[0] = v0.x; va[1] = v0.y; va[2] = v0.z; va[3] = v0.w;
                va[4] = v1.x; va[5] = v1.y; va[6] = v1.z; va[7] = v1.w;
            } else {
#pragma unroll
                for (int j = 0; j < 8; ++j) va[j] = 0.f;
            }
#pragma unroll
            for (int j = 0; j < 8; ++j) {
                ushort h = f2bf(va[j]);
                ah[mt][j] = (short)h;
                al[mt][j] = (short)f2bf(va[j] - bf2f(h));
            }
        }
#pragma unroll
        for (int nt = 0; nt < 8; ++nt) {
            bf16x8 wh = *(const bf16x8*)(WAhi + (size_t)(nt * 16 + l16) * DD + k0);
            bf16x8 wl = *(const bf16x8*)(WAlo + (size_t)(nt * 16 + l16) * DD + k0);
#pragma unroll
            for (int mt = 0; mt < 2; ++mt) {
                acc[mt][nt] = __builtin_amdgcn_mfma_f32_16x16x32_bf16(ah[mt], wh, acc[mt][nt], 0, 0, 0);
                acc[mt][nt] = __builtin_amdgcn_mfma_f32_16x16x32_bf16(al[mt], wh, acc[mt][nt], 0, 0, 0);
                acc[mt][nt] = __builtin_amdgcn_mfma_f32_16x16x32_bf16(ah[mt], wl, acc[mt][nt], 0, 0, 0);
            }
        }
    }

    // ---- pass 2: G (half) ----
    if constexpr (FUSED) {
#pragma unroll
        for (int kk = 0; kk < 4; ++kk) {
            int k0 = kk * 32 + koff;
            bf16x8 gh[2], gl[2];
#pragma unroll
            for (int mt = 0; mt < 2; ++mt) {
                int row = rbase + mt * 16 + l16;
                float va[8];
                if (row < nrows) {
                    union { bf16x8 v; __half h[8]; } u;
                    u.v = *(const bf16x8*)(G + (size_t)row * DD + k0);
#pragma unroll
                    for (int j = 0; j < 8; ++j) va[j] = __half2float(u.h[j]);
                } else {
#pragma unroll
                    for (int j = 0; j < 8; ++j) va[j] = 0.f;
                }
#pragma unroll
                for (int j = 0; j < 8; ++j) {
                    ushort h = f2bf(va[j]);
                    gh[mt][j] = (short)h;
                    gl[mt][j] = (short)f2bf(va[j] - bf2f(h));
                }
            }
#pragma unroll
            for (int nt = 0; nt < 8; ++nt) {
                bf16x8 wh = *(const bf16x8*)(WGhi + (size_t)(nt * 16 + l16) * DD + k0);
                bf16x8 wl = *(const bf16x8*)(WGlo + (size_t)(nt * 16 + l16) * DD + k0);
#pragma unroll
                for (int mt = 0; mt < 2; ++mt) {
                    acc[mt][nt] = __builtin_amdgcn_mfma_f32_16x16x32_bf16(gh[mt], wh, acc[mt][nt], 0, 0, 0);
                    acc[mt][nt] = __builtin_amdgcn_mfma_f32_16x16x32_bf16(gl[mt], wh, acc[mt][nt], 0, 0, 0);
                    acc[mt][nt] = __builtin_amdgcn_mfma_f32_16x16x32_bf16(gh[mt], wl, acc[mt][nt], 0, 0, 0);
                }
            }
        }
    }

    // ---- epilogue: bias (+relu)(+l2norm), LDS repack, coalesced store ----
    float bv[8];
#pragma unroll
    for (int nt = 0; nt < 8; ++nt) bv[nt] = bias[nt * 16 + l16];

    if constexpr (EPI == 1) {
        __half* lds = (__half*)smem;
#pragma unroll
        for (int mt = 0; mt < 2; ++mt)
#pragma unroll
            for (int r = 0; r < 4; ++r) {
                int lr = w * 32 + mt * 16 + lg * 4 + r;
#pragma unroll
                for (int nt = 0; nt < 8; ++nt) {
                    float v = fmaxf(acc[mt][nt][r] + bv[nt], 0.f);
                    lds[lr * DD + nt * 16 + l16] = __float2half(v);
                }
            }
        __syncthreads();
        __half* o = (__half*)outv;
#pragma unroll
        for (int it = 0; it < 8; ++it) {
            int idx = it * 256 + tid;
            int r = idx >> 4, cc = idx & 15;
            int row = blk0 + r;
            if (row < nrows)
                *(bf16x8*)(o + (size_t)row * DD + cc * 8) = *(const bf16x8*)(lds + r * DD + cc * 8);
        }
    } else {
        float* lds = (float*)smem;
#pragma unroll
        for (int mt = 0; mt < 2; ++mt)
#pragma unroll
            for (int r = 0; r < 4; ++r) {
                int lr = w * 32 + mt * 16 + lg * 4 + r;
                float vv[8];
                float s = 0.f;
#pragma unroll
                for (int nt = 0; nt < 8; ++nt) {
                    float v = acc[mt][nt][r] + bv[nt];
                    if (EPI == 2) v = fmaxf(v, 0.f);
                    vv[nt] = v;
                    s += v * v;
                }
                if (EPI == 2) {
                    s += __shfl_xor(s, 1);
                    s += __shfl_xor(s, 2);
                    s += __shfl_xor(s, 4);
                    s += __shfl_xor(s, 8);
                    float sc = 1.f / fmaxf(sqrtf(s), 1e-12f);
#pragma unroll
                    for (int nt = 0; nt < 8; ++nt) vv[nt] *= sc;
                }
#pragma unroll
                for (int nt = 0; nt < 8; ++nt) lds[lr * DD + nt * 16 + l16] = vv[nt];
            }
        __syncthreads();
        float* o = (float*)outv;
#pragma unroll
        for (int it = 0; it < 16; ++it) {
            int idx = it * 256 + tid;
            int r = idx >> 5, cc = idx & 31;
            int row = blk0 + r;
            if (row < nrows)
                *(f32x4*)(o + (size_t)row * DD + cc * 4) = *(const f32x4*)(lds + r * DD + cc * 4);
        }
    }
}

static inline size_t align16(size_t x) { return (x + 15) & ~(size_t)15; }

extern "C" void kernel_launch(void* const* d_in, const int* in_sizes, int n_in,
                              void* d_out, int out_size, void* d_ws, size_t ws_size,
                              hipStream_t stream) {
    const float* x  = (const float*)d_in[0];
    const int* esrc = (const int*)d_in[1];
    const int* edst = (const int*)d_in[2];
    const float* Wm[6];
    for (int i = 0; i < 6; ++i) Wm[i] = (const float*)d_in[3 + i];
    const float* bpool0 = (const float*)d_in[9];
    const float* b0     = (const float*)d_in[10];
    const float* bpool1 = (const float*)d_in[11];
    const float* b1     = (const float*)d_in[12];

    int N = in_sizes[0] / DD;
    int E = in_sizes[1];
    int NB = (N + BK_NODES - 1) >> BK_SHIFT;   // 782 buckets for N=50000 (must be <= 1024)

    // workspace layout
    char* p = (char*)d_ws;
    ushort* Whi   = (ushort*)p;   p += align16((size_t)6 * 16384 * 2);
    ushort* Wlo   = (ushort*)p;   p += align16((size_t)6 * 16384 * 2);
    __half* m     = (__half*)p;   p += align16((size_t)N * DD * 2);
    __half* agg   = (__half*)p;   p += align16((size_t)N * DD * 2);
    int* bcnt     = (int*)p;      p += align16((size_t)NB * 4);
    int* bptr     = (int*)p;      p += align16((size_t)(NB + 1) * 4);
    int* bcur     = (int*)p;      p += align16((size_t)NB * 4);
    int* rowptr   = (int*)p;      p += align16((size_t)(N + 1) * 4);
    unsigned* ebuf = (unsigned*)p; p += align16((size_t)E * 4);
    int* csr_src  = (int*)p;      p += align16((size_t)E * 4);

    float* out_h   = (float*)d_out;                  // output 0: final layer
    float* out_enc = (float*)d_out + (size_t)N * DD; // output 1: enc_feat_input

    // prep: weight bf16 hi/lo split + CSR by dst (bucketed, write-local)
    prep_w<<<384, 256, 0, stream>>>(Wm[0], Wm[1], Wm[2], Wm[3], Wm[4], Wm[5], Whi, Wlo);
    hipMemsetAsync(bcnt, 0, (size_t)NB * 4, stream);
    bucket_hist<<<256, 256, NB * 4, stream>>>(edst, bcnt, E, NB);
    bucket_scan<<<1, 1024, 0, stream>>>(bcnt, bptr, bcur, NB);
    bin_edges<<<(E + 255) / 256, 256, 0, stream>>>(esrc, edst, bcur, ebuf, E);
    build_csr<<<NB, 256, 0, stream>>>(ebuf, bptr, rowptr, csr_src, N);

    int gb = (N + 127) / 128;
    int sb = (N + 3) / 4;

    // layer 0
    gemm_mfma<1, false><<<gb, 256, 32768, stream>>>(x, Whi + 0 * 16384, Wlo + 0 * 16384,
                                                    nullptr, nullptr, nullptr, bpool0, m, N);
    segmax_half<<<sb, 256, 0, stream>>>(m, rowptr, csr_src, agg, N);
    gemm_mfma<2, true><<<gb, 256, 65536, stream>>>(x, Whi + 1 * 16384, Wlo + 1 * 16384,
                                                   agg, Whi + 2 * 16384, Wlo + 2 * 16384, b0, out_enc, N);

    // layer 1
    gemm_mfma<1, false><<<gb, 256, 32768, stream>>>(out_enc, Whi + 3 * 16384, Wlo + 3 * 16384,
                                                    nullptr, nullptr, nullptr, bpool1, m, N);
    segmax_half<<<sb, 256, 0, stream>>>(m, rowptr, csr_src, agg, N);
    gemm_mfma<0, true><<<gb, 256, 65536, stream>>>(out_enc, Whi + 4 * 16384, Wlo + 4 * 16384,
                                                   agg, Whi + 5 * 16384, Wlo + 5 * 16384, b1, out_h, N);
}

// Round 5
// 250.670 us; speedup vs baseline: 1.6851x; 1.6851x over previous
//
#include <hip/hip_runtime.h>
#include <hip/hip_fp16.h>

#define DD 128
#define BK_SHIFT 6
#define BK_NODES 64    // nodes per bucket
#define NBLK 256       // edge-chunk blocks for binning
#define SCAN_T 1024
#define SCAN_E 8
#define SCAN_CHUNK (SCAN_T * SCAN_E)   // 8192

typedef __attribute__((ext_vector_type(8))) short bf16x8;
typedef __attribute__((ext_vector_type(4))) float f32x4;

static __device__ __forceinline__ ushort f2bf(float f) {
    unsigned u = __float_as_uint(f);
    u = u + 0x7FFF + ((u >> 16) & 1);   // RNE
    return (ushort)(u >> 16);
}
static __device__ __forceinline__ float bf2f(ushort h) {
    return __uint_as_float(((unsigned)h) << 16);
}

// ---------------- weights -> bf16 hi/lo split ----------------
__global__ void prep_w(const float* __restrict__ W0, const float* __restrict__ W1,
                       const float* __restrict__ W2, const float* __restrict__ W3,
                       const float* __restrict__ W4, const float* __restrict__ W5,
                       ushort* __restrict__ Whi, ushort* __restrict__ Wlo) {
    int idx = blockIdx.x * 256 + threadIdx.x;   // 0 .. 6*16384-1
    int wi = idx >> 14;
    int off = idx & 16383;
    float a;
    switch (wi) {
        case 0: a = W0[off]; break;
        case 1: a = W1[off]; break;
        case 2: a = W2[off]; break;
        case 3: a = W3[off]; break;
        case 4: a = W4[off]; break;
        default: a = W5[off]; break;
    }
    ushort h = f2bf(a);
    Whi[idx] = h;
    Wlo[idx] = f2bf(a - bf2f(h));
}

// ---------------- CSR stage 1: per-(bucket,block) histogram, LDS only ----------------
__global__ __launch_bounds__(256) void hist2d_kernel(const int* __restrict__ dst,
                                                     int* __restrict__ hist2d,
                                                     int E, int NB, int chunk) {
    extern __shared__ int h[];   // NB ints
    int t = threadIdx.x, b = blockIdx.x;
    for (int i = t; i < NB; i += 256) h[i] = 0;
    __syncthreads();
    int e0 = b * chunk, e1 = min(e0 + chunk, E);
    for (int e = e0 + t; e < e1; e += 256)
        atomicAdd(&h[dst[e] >> BK_SHIFT], 1);
    __syncthreads();
    for (int i = t; i < NB; i += 256) hist2d[i * NBLK + b] = h[i];
}

// ---------------- CSR stage 2: multi-block exclusive scan, in place ----------------
__global__ __launch_bounds__(SCAN_T) void partial_reduce(const int* __restrict__ data,
                                                         int* __restrict__ bsum, int n) {
    __shared__ int s[SCAN_T];
    int t = threadIdx.x;
    int i0 = blockIdx.x * SCAN_CHUNK + t * SCAN_E;
    int sum = 0;
#pragma unroll
    for (int u = 0; u < SCAN_E; ++u) {
        int i = i0 + u;
        sum += (i < n) ? data[i] : 0;
    }
    s[t] = sum;
    __syncthreads();
    for (int off = SCAN_T / 2; off > 0; off >>= 1) {
        if (t < off) s[t] += s[t + off];
        __syncthreads();
    }
    if (t == 0) bsum[blockIdx.x] = s[0];
}

__global__ __launch_bounds__(SCAN_T) void scan_excl_inplace(int* __restrict__ data,
                                                            const int* __restrict__ bsum, int n) {
    __shared__ int s[SCAN_T];
    int t = threadIdx.x;
    int b = blockIdx.x;
    int carry = 0;
    for (int k = 0; k < b; ++k) carry += bsum[k];   // few blocks; cheap, uniform
    int i0 = b * SCAN_CHUNK + t * SCAN_E;
    int v[SCAN_E];
    int sum = 0;
#pragma unroll
    for (int u = 0; u < SCAN_E; ++u) {
        v[u] = (i0 + u < n) ? data[i0 + u] : 0;
        sum += v[u];
    }
    s[t] = sum;
    __syncthreads();
    for (int off = 1; off < SCAN_T; off <<= 1) {
        int x = (t >= off) ? s[t - off] : 0;
        __syncthreads();
        s[t] += x;
        __syncthreads();
    }
    int run = s[t] - sum + carry;   // exclusive prefix of this thread's first elem
#pragma unroll
    for (int u = 0; u < SCAN_E; ++u) {
        int i = i0 + u;
        if (i < n) {
            data[i] = run;
            run += v[u];
        }
    }
}

// ---------------- CSR stage 3: bin edges via LDS cursors (no global atomics) ----------------
__global__ __launch_bounds__(256) void bin_edges2(const int* __restrict__ src,
                                                  const int* __restrict__ dst,
                                                  const int* __restrict__ base,   // scanned hist2d
                                                  unsigned* __restrict__ ebuf,
                                                  int E, int NB, int chunk) {
    extern __shared__ int h[];   // NB cursors
    int t = threadIdx.x, b = blockIdx.x;
    for (int i = t; i < NB; i += 256) h[i] = base[i * NBLK + b];
    __syncthreads();
    int e0 = b * chunk, e1 = min(e0 + chunk, E);
    for (int e = e0 + t; e < e1; e += 256) {
        int d = dst[e];
        int p = atomicAdd(&h[d >> BK_SHIFT], 1);
        ebuf[p] = ((unsigned)src[e] << BK_SHIFT) | (unsigned)(d & (BK_NODES - 1));
    }
}

// ---------------- CSR stage 4: per-bucket rowptr + csr scatter ----------------
__global__ __launch_bounds__(256) void build_csr(const unsigned* __restrict__ ebuf,
                                                 const int* __restrict__ base,
                                                 int* __restrict__ rowptr,
                                                 int* __restrict__ csr_src, int N, int NB, int E) {
    __shared__ int cnt[BK_NODES];
    __shared__ int cur[BK_NODES];
    int b = blockIdx.x;
    int t = threadIdx.x;
    int beg = base[b * NBLK];
    int end = (b == NB - 1) ? E : base[(b + 1) * NBLK];
    if (b == 0 && t == 0) rowptr[0] = 0;
    if (t < BK_NODES) cnt[t] = 0;
    __syncthreads();
    for (int e = beg + t; e < end; e += 256)
        atomicAdd(&cnt[ebuf[e] & (BK_NODES - 1)], 1);
    __syncthreads();
    if (t < 64) {   // one wave: scan 64 counts
        int v = cnt[t];
        int inc = v;
#pragma unroll
        for (int off = 1; off < 64; off <<= 1) {
            int x = __shfl_up(inc, off);
            if (t >= off) inc += x;
        }
        cur[t] = beg + inc - v;          // exclusive
        int node = b * BK_NODES + t;
        if (node < N) rowptr[node + 1] = beg + inc;
    }
    __syncthreads();
    for (int e = beg + t; e < end; e += 256) {
        unsigned v = ebuf[e];
        int p = atomicAdd(&cur[v & (BK_NODES - 1)], 1);
        csr_src[p] = (int)(v >> BK_SHIFT);
    }
}

// ---------------- segment max gather (half rows), 8-deep ILP ----------------
__global__ __launch_bounds__(256) void segmax_half(const __half* __restrict__ m,
                                                   const int* __restrict__ rowptr,
                                                   const int* __restrict__ csr_src,
                                                   __half* __restrict__ agg, int n) {
    int node = blockIdx.x * 4 + (threadIdx.x >> 6);
    if (node >= n) return;
    int lane = threadIdx.x & 63;
    int beg = rowptr[node], end = rowptr[node + 1];
    const __half* mp = m + lane * 2;
    float2 mx[8];
#pragma unroll
    for (int u = 0; u < 8; ++u) mx[u] = make_float2(0.f, 0.f);   // relu'd inputs >= 0
    int e = beg;
    for (; e + 8 <= end; e += 8) {
#pragma unroll
        for (int u = 0; u < 8; ++u) {
            int s = csr_src[e + u];
            float2 v = __half22float2(*(const __half2*)(mp + (size_t)s * DD));
            mx[u].x = fmaxf(mx[u].x, v.x);
            mx[u].y = fmaxf(mx[u].y, v.y);
        }
    }
    for (; e < end; ++e) {
        int s = csr_src[e];
        float2 v = __half22float2(*(const __half2*)(mp + (size_t)s * DD));
        mx[0].x = fmaxf(mx[0].x, v.x);
        mx[0].y = fmaxf(mx[0].y, v.y);
    }
#pragma unroll
    for (int u = 4; u > 0; u >>= 1)
#pragma unroll
        for (int k = 0; k < u; ++k) {
            mx[k].x = fmaxf(mx[k].x, mx[k + u].x);
            mx[k].y = fmaxf(mx[k].y, mx[k + u].y);
        }
    *(__half2*)(agg + (size_t)node * DD + lane * 2) = __float22half2_rn(mx[0]);
}

// ---------------- MFMA GEMM: out = A@WA^T (+ G@WG^T) + bias ----------------
// split-bf16: X = hi + lo; X*W ~= hi*Whi + lo*Whi + hi*Wlo  (error ~2^-16 rel)
// EPI: 0 = none (f32 out), 1 = relu (half out), 2 = relu + row-L2-norm (f32 out)
template <int EPI, bool FUSED>
__global__ __launch_bounds__(256, 2) void gemm_mfma(
    const float* __restrict__ A, const ushort* __restrict__ WAhi, const ushort* __restrict__ WAlo,
    const __half* __restrict__ G, const ushort* __restrict__ WGhi, const ushort* __restrict__ WGlo,
    const float* __restrict__ bias, void* __restrict__ outv, int nrows) {
    extern __shared__ char smem[];
    int tid = threadIdx.x;
    int lane = tid & 63;
    int w = tid >> 6;
    int l16 = lane & 15;
    int lg = lane >> 4;
    int koff = lg * 8;
    int blk0 = blockIdx.x * 128;
    int rbase = blk0 + w * 32;

    f32x4 zero4 = {0.f, 0.f, 0.f, 0.f};
    f32x4 acc[2][8];
#pragma unroll
    for (int mt = 0; mt < 2; ++mt)
#pragma unroll
        for (int nt = 0; nt < 8; ++nt) acc[mt][nt] = zero4;

    // ---- pass 1: A (f32) ----
#pragma unroll
    for (int kk = 0; kk < 4; ++kk) {
        int k0 = kk * 32 + koff;
        bf16x8 ah[2], al[2];
#pragma unroll
        for (int mt = 0; mt < 2; ++mt) {
            int row = rbase + mt * 16 + l16;
            float va[8];
            if (row < nrows) {
                float4 v0 = *(const float4*)(A + (size_t)row * DD + k0);
                float4 v1 = *(const float4*)(A + (size_t)row * DD + k0 + 4);
                va[0] = v0.x; va[1] = v0.y; va[2] = v0.z; va[3] = v0.w;
                va[4] = v1.x; va[5] = v1.y; va[6] = v1.z; va[7] = v1.w;
            } else {
#pragma unroll
                for (int j = 0; j < 8; ++j) va[j] = 0.f;
            }
#pragma unroll
            for (int j = 0; j < 8; ++j) {
                ushort h = f2bf(va[j]);
                ah[mt][j] = (short)h;
                al[mt][j] = (short)f2bf(va[j] - bf2f(h));
            }
        }
#pragma unroll
        for (int nt = 0; nt < 8; ++nt) {
            bf16x8 wh = *(const bf16x8*)(WAhi + (size_t)(nt * 16 + l16) * DD + k0);
            bf16x8 wl = *(const bf16x8*)(WAlo + (size_t)(nt * 16 + l16) * DD + k0);
#pragma unroll
            for (int mt = 0; mt < 2; ++mt) {
                acc[mt][nt] = __builtin_amdgcn_mfma_f32_16x16x32_bf16(ah[mt], wh, acc[mt][nt], 0, 0, 0);
                acc[mt][nt] = __builtin_amdgcn_mfma_f32_16x16x32_bf16(al[mt], wh, acc[mt][nt], 0, 0, 0);
                acc[mt][nt] = __builtin_amdgcn_mfma_f32_16x16x32_bf16(ah[mt], wl, acc[mt][nt], 0, 0, 0);
            }
        }
    }

    // ---- pass 2: G (half) ----
    if constexpr (FUSED) {
#pragma unroll
        for (int kk = 0; kk < 4; ++kk) {
            int k0 = kk * 32 + koff;
            bf16x8 gh[2], gl[2];
#pragma unroll
            for (int mt = 0; mt < 2; ++mt) {
                int row = rbase + mt * 16 + l16;
                float va[8];
                if (row < nrows) {
                    union { bf16x8 v; __half h[8]; } u;
                    u.v = *(const bf16x8*)(G + (size_t)row * DD + k0);
#pragma unroll
                    for (int j = 0; j < 8; ++j) va[j] = __half2float(u.h[j]);
                } else {
#pragma unroll
                    for (int j = 0; j < 8; ++j) va[j] = 0.f;
                }
#pragma unroll
                for (int j = 0; j < 8; ++j) {
                    ushort h = f2bf(va[j]);
                    gh[mt][j] = (short)h;
                    gl[mt][j] = (short)f2bf(va[j] - bf2f(h));
                }
            }
#pragma unroll
            for (int nt = 0; nt < 8; ++nt) {
                bf16x8 wh = *(const bf16x8*)(WGhi + (size_t)(nt * 16 + l16) * DD + k0);
                bf16x8 wl = *(const bf16x8*)(WGlo + (size_t)(nt * 16 + l16) * DD + k0);
#pragma unroll
                for (int mt = 0; mt < 2; ++mt) {
                    acc[mt][nt] = __builtin_amdgcn_mfma_f32_16x16x32_bf16(gh[mt], wh, acc[mt][nt], 0, 0, 0);
                    acc[mt][nt] = __builtin_amdgcn_mfma_f32_16x16x32_bf16(gl[mt], wh, acc[mt][nt], 0, 0, 0);
                    acc[mt][nt] = __builtin_amdgcn_mfma_f32_16x16x32_bf16(gh[mt], wl, acc[mt][nt], 0, 0, 0);
                }
            }
        }
    }

    // ---- epilogue: bias (+relu)(+l2norm), LDS repack, coalesced store ----
    float bv[8];
#pragma unroll
    for (int nt = 0; nt < 8; ++nt) bv[nt] = bias[nt * 16 + l16];

    if constexpr (EPI == 1) {
        __half* lds = (__half*)smem;
#pragma unroll
        for (int mt = 0; mt < 2; ++mt)
#pragma unroll
            for (int r = 0; r < 4; ++r) {
                int lr = w * 32 + mt * 16 + lg * 4 + r;
#pragma unroll
                for (int nt = 0; nt < 8; ++nt) {
                    float v = fmaxf(acc[mt][nt][r] + bv[nt], 0.f);
                    lds[lr * DD + nt * 16 + l16] = __float2half(v);
                }
            }
        __syncthreads();
        __half* o = (__half*)outv;
#pragma unroll
        for (int it = 0; it < 8; ++it) {
            int idx = it * 256 + tid;
            int r = idx >> 4, cc = idx & 15;
            int row = blk0 + r;
            if (row < nrows)
                *(bf16x8*)(o + (size_t)row * DD + cc * 8) = *(const bf16x8*)(lds + r * DD + cc * 8);
        }
    } else {
        float* lds = (float*)smem;
#pragma unroll
        for (int mt = 0; mt < 2; ++mt)
#pragma unroll
            for (int r = 0; r < 4; ++r) {
                int lr = w * 32 + mt * 16 + lg * 4 + r;
                float vv[8];
                float s = 0.f;
#pragma unroll
                for (int nt = 0; nt < 8; ++nt) {
                    float v = acc[mt][nt][r] + bv[nt];
                    if (EPI == 2) v = fmaxf(v, 0.f);
                    vv[nt] = v;
                    s += v * v;
                }
                if (EPI == 2) {
                    s += __shfl_xor(s, 1);
                    s += __shfl_xor(s, 2);
                    s += __shfl_xor(s, 4);
                    s += __shfl_xor(s, 8);
                    float sc = 1.f / fmaxf(sqrtf(s), 1e-12f);
#pragma unroll
                    for (int nt = 0; nt < 8; ++nt) vv[nt] *= sc;
                }
#pragma unroll
                for (int nt = 0; nt < 8; ++nt) lds[lr * DD + nt * 16 + l16] = vv[nt];
            }
        __syncthreads();
        float* o = (float*)outv;
#pragma unroll
        for (int it = 0; it < 16; ++it) {
            int idx = it * 256 + tid;
            int r = idx >> 5, cc = idx & 31;
            int row = blk0 + r;
            if (row < nrows)
                *(f32x4*)(o + (size_t)row * DD + cc * 4) = *(const f32x4*)(lds + r * DD + cc * 4);
        }
    }
}

static inline size_t align16(size_t x) { return (x + 15) & ~(size_t)15; }

extern "C" void kernel_launch(void* const* d_in, const int* in_sizes, int n_in,
                              void* d_out, int out_size, void* d_ws, size_t ws_size,
                              hipStream_t stream) {
    const float* x  = (const float*)d_in[0];
    const int* esrc = (const int*)d_in[1];
    const int* edst = (const int*)d_in[2];
    const float* Wm[6];
    for (int i = 0; i < 6; ++i) Wm[i] = (const float*)d_in[3 + i];
    const float* bpool0 = (const float*)d_in[9];
    const float* b0     = (const float*)d_in[10];
    const float* bpool1 = (const float*)d_in[11];
    const float* b1     = (const float*)d_in[12];

    int N = in_sizes[0] / DD;
    int E = in_sizes[1];
    int NB = (N + BK_NODES - 1) >> BK_SHIFT;       // 782 buckets for N=50000
    int chunk = (E + NBLK - 1) / NBLK;             // edges per binning block
    int nh = NB * NBLK;                            // hist2d elements (200192)
    int nscan = (nh + SCAN_CHUNK - 1) / SCAN_CHUNK;

    // workspace layout
    char* p = (char*)d_ws;
    ushort* Whi    = (ushort*)p;   p += align16((size_t)6 * 16384 * 2);
    ushort* Wlo    = (ushort*)p;   p += align16((size_t)6 * 16384 * 2);
    __half* m      = (__half*)p;   p += align16((size_t)N * DD * 2);
    __half* agg    = (__half*)p;   p += align16((size_t)N * DD * 2);
    int* hist2d    = (int*)p;      p += align16((size_t)nh * 4);
    int* bsum      = (int*)p;      p += align16((size_t)nscan * 4);
    int* rowptr    = (int*)p;      p += align16((size_t)(N + 1) * 4);
    unsigned* ebuf = (unsigned*)p; p += align16((size_t)E * 4);
    int* csr_src   = (int*)p;      p += align16((size_t)E * 4);

    float* out_h   = (float*)d_out;                  // output 0: final layer
    float* out_enc = (float*)d_out + (size_t)N * DD; // output 1: enc_feat_input

    // prep: weight bf16 hi/lo split + CSR by dst (bucketed, atomic-free binning)
    prep_w<<<384, 256, 0, stream>>>(Wm[0], Wm[1], Wm[2], Wm[3], Wm[4], Wm[5], Whi, Wlo);
    hist2d_kernel<<<NBLK, 256, NB * 4, stream>>>(edst, hist2d, E, NB, chunk);
    partial_reduce<<<nscan, SCAN_T, 0, stream>>>(hist2d, bsum, nh);
    scan_excl_inplace<<<nscan, SCAN_T, 0, stream>>>(hist2d, bsum, nh);
    bin_edges2<<<NBLK, 256, NB * 4, stream>>>(esrc, edst, hist2d, ebuf, E, NB, chunk);
    build_csr<<<NB, 256, 0, stream>>>(ebuf, hist2d, rowptr, csr_src, N, NB, E);

    int gb = (N + 127) / 128;
    int sb = (N + 3) / 4;

    // layer 0
    gemm_mfma<1, false><<<gb, 256, 32768, stream>>>(x, Whi + 0 * 16384, Wlo + 0 * 16384,
                                                    nullptr, nullptr, nullptr, bpool0, m, N);
    segmax_half<<<sb, 256, 0, stream>>>(m, rowptr, csr_src, agg, N);
    gemm_mfma<2, true><<<gb, 256, 65536, stream>>>(x, Whi + 1 * 16384, Wlo + 1 * 16384,
                                                   agg, Whi + 2 * 16384, Wlo + 2 * 16384, b0, out_enc, N);

    // layer 1
    gemm_mfma<1, false><<<gb, 256, 32768, stream>>>(out_enc, Whi + 3 * 16384, Wlo + 3 * 16384,
                                                    nullptr, nullptr, nullptr, bpool1, m, N);
    segmax_half<<<sb, 256, 0, stream>>>(m, rowptr, csr_src, agg, N);
    gemm_mfma<0, true><<<gb, 256, 65536, stream>>>(out_enc, Whi + 4 * 16384, Wlo + 4 * 16384,
                                                   agg, Whi + 5 * 16384, Wlo + 5 * 16384, b1, out_h, N);
}